// Round 1
// baseline (1533.387 us; speedup 1.0000x reference)
//
#include <hip/hip_runtime.h>
#include <math.h>

#define LEVELS 16
#define HASHMAP_SIZE (1 << 19)
#define HIDDEN 64
#define N_POINTS 2097152

__global__ __launch_bounds__(256) void nerf_fused_f32(
    const float* __restrict__ x,
    const float* __restrict__ view_dir,
    const float* __restrict__ tables,
    const float* __restrict__ W0,
    const float* __restrict__ b0,
    const float* __restrict__ W1,
    const float* __restrict__ b1,
    const float* __restrict__ W2,
    const float* __restrict__ b2,
    float* __restrict__ out)
{
    __shared__ float W0s[35 * 64];
    __shared__ float b0s[64];
    __shared__ float W1s[64 * 64];
    __shared__ float b1s[64];
    __shared__ float W2s[64 * 4];
    __shared__ float b2s[4];

    const int tid = threadIdx.x;
    for (int i = tid; i < 35 * 64; i += 256) W0s[i] = W0[i];
    for (int i = tid; i < 64 * 64; i += 256) W1s[i] = W1[i];
    for (int i = tid; i < 64 * 4; i += 256) W2s[i] = W2[i];
    if (tid < 64) b0s[tid] = b0[tid];
    if (tid < 64) b1s[tid] = b1[tid];
    if (tid < 4)  b2s[tid] = b2[tid];
    __syncthreads();

    const int gid = blockIdx.x * 256 + tid;

    const float px = x[gid * 3 + 0];
    const float py = x[gid * 3 + 1];
    const float pz = x[gid * 3 + 2];

    // int(16 * 1.5**l) for l in 0..15, exact in f32
    const float res[LEVELS] = {16.f, 24.f, 36.f, 54.f, 81.f, 121.f, 182.f, 273.f,
                               410.f, 615.f, 922.f, 1383.f, 2075.f, 3113.f, 4670.f, 7006.f};

    // ---- Layer 0 (fused with hash-grid gather): acc = W0^T h + b0 ----
    float acc[HIDDEN];
    #pragma unroll
    for (int j = 0; j < HIDDEN; ++j) acc[j] = b0s[j];

    #pragma unroll
    for (int l = 0; l < LEVELS; ++l) {
        const int ix = (int)floorf(px * res[l]);
        const int iy = (int)floorf(py * res[l]);
        const int iz = (int)floorf(pz * res[l]);
        // int32 wrap-multiply hash, Python-mod by 2^19 == mask
        const unsigned h = (unsigned)ix * 73856093u
                         ^ (unsigned)iy * 19349663u
                         ^ (unsigned)iz * 83492791u;
        const unsigned idx = h & (unsigned)(HASHMAP_SIZE - 1);
        const float2 f = *reinterpret_cast<const float2*>(
            tables + ((size_t)l * HASHMAP_SIZE + idx) * 2);
        const float* __restrict__ wa = &W0s[(2 * l + 0) * 64];
        const float* __restrict__ wb = &W0s[(2 * l + 1) * 64];
        #pragma unroll
        for (int j = 0; j < HIDDEN; ++j)
            acc[j] += f.x * wa[j] + f.y * wb[j];
    }
    {
        const float v0 = view_dir[gid * 3 + 0];
        const float v1 = view_dir[gid * 3 + 1];
        const float v2 = view_dir[gid * 3 + 2];
        const float* __restrict__ wa = &W0s[32 * 64];
        const float* __restrict__ wb = &W0s[33 * 64];
        const float* __restrict__ wc = &W0s[34 * 64];
        #pragma unroll
        for (int j = 0; j < HIDDEN; ++j)
            acc[j] += v0 * wa[j] + v1 * wb[j] + v2 * wc[j];
    }
    #pragma unroll
    for (int j = 0; j < HIDDEN; ++j) acc[j] = fmaxf(acc[j], 0.f);

    // ---- Layer 1: acc2 = relu(W1^T acc + b1) ----
    float acc2[HIDDEN];
    #pragma unroll
    for (int j = 0; j < HIDDEN; ++j) acc2[j] = b1s[j];
    #pragma unroll
    for (int k = 0; k < HIDDEN; ++k) {
        const float s = acc[k];
        const float* __restrict__ w = &W1s[k * 64];
        #pragma unroll
        for (int j = 0; j < HIDDEN; ++j) acc2[j] += s * w[j];
    }
    #pragma unroll
    for (int j = 0; j < HIDDEN; ++j) acc2[j] = fmaxf(acc2[j], 0.f);

    // ---- Layer 2: out = W2^T acc2 + b2 ----
    float o0 = b2s[0], o1 = b2s[1], o2 = b2s[2], o3 = b2s[3];
    #pragma unroll
    for (int k = 0; k < HIDDEN; ++k) {
        const float s = acc2[k];
        o0 += s * W2s[k * 4 + 0];
        o1 += s * W2s[k * 4 + 1];
        o2 += s * W2s[k * 4 + 2];
        o3 += s * W2s[k * 4 + 3];
    }

    // rgb = sigmoid(o0..o2), sigma = relu(o3); layout: rgb [N*3] then sigma [N]
    out[(size_t)gid * 3 + 0] = 1.f / (1.f + expf(-o0));
    out[(size_t)gid * 3 + 1] = 1.f / (1.f + expf(-o1));
    out[(size_t)gid * 3 + 2] = 1.f / (1.f + expf(-o2));
    out[(size_t)N_POINTS * 3 + gid] = fmaxf(o3, 0.f);
}

extern "C" void kernel_launch(void* const* d_in, const int* in_sizes, int n_in,
                              void* d_out, int out_size, void* d_ws, size_t ws_size,
                              hipStream_t stream) {
    (void)in_sizes; (void)n_in; (void)d_ws; (void)ws_size; (void)out_size;
    const float* x        = (const float*)d_in[0];
    const float* view_dir = (const float*)d_in[1];
    const float* tables   = (const float*)d_in[2];
    const float* W0       = (const float*)d_in[3];
    const float* b0       = (const float*)d_in[4];
    const float* W1       = (const float*)d_in[5];
    const float* b1       = (const float*)d_in[6];
    const float* W2       = (const float*)d_in[7];
    const float* b2       = (const float*)d_in[8];
    float* out = (float*)d_out;

    const int block = 256;
    const int grid = N_POINTS / block;  // 8192
    nerf_fused_f32<<<grid, block, 0, stream>>>(x, view_dir, tables,
                                               W0, b0, W1, b1, W2, b2, out);
}

// Round 2
// 532.633 us; speedup vs baseline: 2.8789x; 2.8789x over previous
//
#include <hip/hip_runtime.h>
#include <math.h>

#define LEVELS 16
#define HASHMAP_SIZE (1 << 19)
#define N_POINTS 2097152

typedef __attribute__((ext_vector_type(8))) short bf16x8;
typedef __attribute__((ext_vector_type(4))) float f32x4;

__device__ __forceinline__ unsigned short f2bf(float f) {
    unsigned u = __builtin_bit_cast(unsigned, f);
    u += 0x7FFFu + ((u >> 16) & 1u);   // RNE
    return (unsigned short)(u >> 16);
}
__device__ __forceinline__ float bf2f(unsigned short s) {
    unsigned u = ((unsigned)s) << 16;
    return __builtin_bit_cast(float, u);
}

// LDS byte-swizzle: XOR the 16B-chunk bits with (row&7) -> conflict-free-ish
// ds_read_b128 of per-lane rows (G4 / T2).
__device__ __forceinline__ unsigned swz(unsigned row, unsigned colbyte) {
    return row * 128u + (colbyte ^ ((row & 7u) << 4));
}

__global__ __launch_bounds__(256) void nerf_mfma(
    const float* __restrict__ x,
    const float* __restrict__ view_dir,
    const float* __restrict__ tables,
    const float* __restrict__ W0, const float* __restrict__ b0,
    const float* __restrict__ W1, const float* __restrict__ b1,
    const float* __restrict__ W2, const float* __restrict__ b2,
    float* __restrict__ out)
{
    __shared__ __align__(16) unsigned short acts[256 * 64]; // 32KB, reused in place per layer
    __shared__ __align__(16) unsigned short w0t[64 * 64];   // 8KB  W0^T [n][k], k>=35 zero
    __shared__ __align__(16) unsigned short w1t[64 * 64];   // 8KB  W1^T [n][k]
    __shared__ float w2s[64 * 4];
    __shared__ float b0s[64], b1s[64], b2s[4];

    char* const actsb = (char*)acts;
    char* const w0b   = (char*)w0t;
    char* const w1b   = (char*)w1t;

    const int tid = threadIdx.x;

    // ---- stage weights: transpose to [n][k], bf16, swizzled ----
    for (int i = tid; i < 4096; i += 256) {
        int n = i & 63, k = i >> 6;               // consecutive tid -> consecutive n (coalesced)
        float v0 = (k < 35) ? W0[k * 64 + n] : 0.f;
        float v1 = W1[k * 64 + n];
        unsigned byte = swz((unsigned)n, (unsigned)(k * 2));
        *(unsigned short*)(w0b + byte) = f2bf(v0);
        *(unsigned short*)(w1b + byte) = f2bf(v1);
    }
    w2s[tid] = W2[tid];                            // 256 elements exactly
    if (tid < 64) { b0s[tid] = b0[tid]; b1s[tid] = b1[tid]; }
    if (tid < 4)  b2s[tid] = b2[tid];
    __syncthreads();   // only barrier in the kernel (weights are cross-wave)

    // ---- gather: one point per thread, build bf16 row, write to LDS ----
    const int gid = blockIdx.x * 256 + tid;
    const float px = x[gid * 3 + 0];
    const float py = x[gid * 3 + 1];
    const float pz = x[gid * 3 + 2];

    const float res[LEVELS] = {16.f, 24.f, 36.f, 54.f, 81.f, 121.f, 182.f, 273.f,
                               410.f, 615.f, 922.f, 1383.f, 2075.f, 3113.f, 4670.f, 7006.f};

    unsigned fw[18];
    #pragma unroll
    for (int l = 0; l < LEVELS; ++l) {
        const int ix = (int)floorf(px * res[l]);
        const int iy = (int)floorf(py * res[l]);
        const int iz = (int)floorf(pz * res[l]);
        const unsigned h = (unsigned)ix * 73856093u
                         ^ (unsigned)iy * 19349663u
                         ^ (unsigned)iz * 83492791u;
        const unsigned idx = h & (unsigned)(HASHMAP_SIZE - 1);
        const float2 f = *reinterpret_cast<const float2*>(
            tables + ((size_t)l * HASHMAP_SIZE + idx) * 2);
        fw[l] = (unsigned)f2bf(f.x) | ((unsigned)f2bf(f.y) << 16);
    }
    fw[16] = (unsigned)f2bf(view_dir[gid * 3 + 0])
           | ((unsigned)f2bf(view_dir[gid * 3 + 1]) << 16);
    fw[17] = (unsigned)f2bf(view_dir[gid * 3 + 2]);

    {
        const unsigned row = (unsigned)tid;
        #pragma unroll
        for (int c = 0; c < 8; ++c) {
            int4 v;
            if (c < 4)      v = make_int4((int)fw[4*c], (int)fw[4*c+1], (int)fw[4*c+2], (int)fw[4*c+3]);
            else if (c == 4) v = make_int4((int)fw[16], (int)fw[17], 0, 0);
            else             v = make_int4(0, 0, 0, 0);
            *(int4*)(actsb + swz(row, (unsigned)(c * 16))) = v;
        }
    }
    // No barrier: wave w's MFMA reads only rows [64w, 64w+64) == its own threads' rows.

    const int lane = tid & 63;
    const int lr = lane & 15;     // A: row-in-tile / B: col / C: col
    const int lg = lane >> 4;     // k-group / C row-group
    const unsigned Rbase = (unsigned)(tid & ~63);   // this wave's first row

    // ==== Layer 0: acts[256x64(k,pad)] @ W0[64x64] -> relu -> acts (in place) ====
    // ==== Layer 1: same with W1 ====
    #pragma unroll
    for (int layer = 0; layer < 2; ++layer) {
        char* const wb = (layer == 0) ? w0b : w1b;
        const float* const bs = (layer == 0) ? b0s : b1s;

        bf16x8 bw[8];
        #pragma unroll
        for (int nt = 0; nt < 4; ++nt)
            #pragma unroll
            for (int ks = 0; ks < 2; ++ks) {
                const unsigned n = (unsigned)(nt * 16 + lr);
                bw[nt * 2 + ks] = *(const bf16x8*)(wb + swz(n, (unsigned)((ks * 4 + lg) * 16)));
            }

        #pragma unroll
        for (int rt = 0; rt < 4; ++rt) {
            bf16x8 aa[2];
            #pragma unroll
            for (int ks = 0; ks < 2; ++ks) {
                const unsigned row = Rbase + (unsigned)(rt * 16 + lr);
                aa[ks] = *(const bf16x8*)(actsb + swz(row, (unsigned)((ks * 4 + lg) * 16)));
            }
            f32x4 acc[4];
            #pragma unroll
            for (int nt = 0; nt < 4; ++nt) {
                const float bv = bs[nt * 16 + lr];
                f32x4 c = {bv, bv, bv, bv};
                c = __builtin_amdgcn_mfma_f32_16x16x32_bf16(aa[0], bw[nt * 2 + 0], c, 0, 0, 0);
                c = __builtin_amdgcn_mfma_f32_16x16x32_bf16(aa[1], bw[nt * 2 + 1], c, 0, 0, 0);
                acc[nt] = c;
            }
            // relu + bf16 + in-place writeback of this row-tile (reads above precede, same wave)
            #pragma unroll
            for (int nt = 0; nt < 4; ++nt)
                #pragma unroll
                for (int r = 0; r < 4; ++r) {
                    const float v = fmaxf(acc[nt][r], 0.f);
                    const unsigned row = Rbase + (unsigned)(rt * 16 + lg * 4 + r);
                    const unsigned col = (unsigned)(nt * 16 + lr);
                    *(unsigned short*)(actsb + swz(row, col * 2)) = f2bf(v);
                }
        }
    }

    // ==== Layer 2 (64 -> 4) per-thread VALU + activations ====
    {
        float h[64];
        const unsigned row = (unsigned)tid;
        #pragma unroll
        for (int c = 0; c < 8; ++c) {
            const bf16x8 v = *(const bf16x8*)(actsb + swz(row, (unsigned)(c * 16)));
            #pragma unroll
            for (int j = 0; j < 8; ++j) h[c * 8 + j] = bf2f((unsigned short)v[j]);
        }
        float o0 = b2s[0], o1 = b2s[1], o2 = b2s[2], o3 = b2s[3];
        #pragma unroll
        for (int k = 0; k < 64; ++k) {
            const float s = h[k];
            o0 += s * w2s[k * 4 + 0];
            o1 += s * w2s[k * 4 + 1];
            o2 += s * w2s[k * 4 + 2];
            o3 += s * w2s[k * 4 + 3];
        }
        out[(size_t)gid * 3 + 0] = 1.f / (1.f + expf(-o0));
        out[(size_t)gid * 3 + 1] = 1.f / (1.f + expf(-o1));
        out[(size_t)gid * 3 + 2] = 1.f / (1.f + expf(-o2));
        out[(size_t)N_POINTS * 3 + gid] = fmaxf(o3, 0.f);
    }
}

extern "C" void kernel_launch(void* const* d_in, const int* in_sizes, int n_in,
                              void* d_out, int out_size, void* d_ws, size_t ws_size,
                              hipStream_t stream) {
    (void)in_sizes; (void)n_in; (void)d_ws; (void)ws_size; (void)out_size;
    const float* x        = (const float*)d_in[0];
    const float* view_dir = (const float*)d_in[1];
    const float* tables   = (const float*)d_in[2];
    const float* W0       = (const float*)d_in[3];
    const float* b0       = (const float*)d_in[4];
    const float* W1       = (const float*)d_in[5];
    const float* b1       = (const float*)d_in[6];
    const float* W2       = (const float*)d_in[7];
    const float* b2       = (const float*)d_in[8];
    float* out = (float*)d_out;

    const int block = 256;
    const int grid = N_POINTS / block;  // 8192
    nerf_mfma<<<grid, block, 0, stream>>>(x, view_dir, tables,
                                          W0, b0, W1, b1, W2, b2, out);
}